// Round 2
// 440.853 us; speedup vs baseline: 1.0169x; 1.0169x over previous
//
#include <hip/hip_runtime.h>
#include <math.h>

#define N_SRC   200000
#define N_DST   50000
#define N_EDGES 800000
#define N_IN    256
#define N_OUT   128
#define CAP     64        // padded-CSR slots/row; P(deg>64 | Binom(800K,1/50K)) ~ 1e-18/row

// ---- workspace layout (bytes), all 16B-aligned ----
#define WS_CNT   0            // int[50000] (+pad)
#define WS_WTW   204800       // ushort[128*256] bf16 (W_w^T)
#define WS_WTB   270336       // ushort[128*256] bf16 (W_b^T)
#define WS_SELF  335872       // ushort[50000*128] bf16
#define WS_Y     13135872     // ushort[200000*128] bf16
#define WS_CSR   64335872     // int2[50000*64]
// total ~90 MB

typedef short  bf16x8 __attribute__((ext_vector_type(8)));
typedef unsigned short u16x8 __attribute__((ext_vector_type(8)));
typedef float  f32x4  __attribute__((ext_vector_type(4)));

__device__ inline unsigned short f2bf(float f) {
    unsigned u = __builtin_bit_cast(unsigned, f);
    u += 0x7fffu + ((u >> 16) & 1u);           // RNE
    return (unsigned short)(u >> 16);
}
__device__ inline float bf2f(unsigned short h) {
    return __builtin_bit_cast(float, (unsigned)h << 16);
}

// ---------------- init: weight transpose+bf16, zero cnt ----------------
// 256 blocks x 256 threads = 65536 = 2*128*256
__global__ __launch_bounds__(256) void k_init(const float* __restrict__ Ww,
                                              const float* __restrict__ Wb,
                                              unsigned short* __restrict__ Wtw,
                                              unsigned short* __restrict__ Wtb,
                                              int* __restrict__ cnt) {
    int tot = blockIdx.x * 256 + threadIdx.x;
    int sel = tot >> 15;
    int idx = tot & 32767;
    int n = idx >> 8, k = idx & 255;
    const float* src = sel ? Wb : Ww;
    unsigned short* dst = sel ? Wtb : Wtw;
    dst[n * 256 + k] = f2bf(src[k * 128 + n]);
    if (tot < N_DST) cnt[tot] = 0;
}

// ---------------- mega: scatter (padded CSR) + both MFMA GEMMs ----------------
// blocks [0,3125): scatter 800000 edges
// blocks [3125,6250): y = x @ W_w           (200000 rows)
// blocks [6250,7032): self = x[sn] @ W_b    (50000 rows)
#define GSCAT 3125
#define GBIG  3125
#define GSELF 782
#define LDT 88          // padded LDS row stride (bf16 elems)
#define EPS 132         // epilogue LDS stride

// tile-kt global loads into register buffers (ping/pong, depth-2 prefetch).
// All array indices are compile-time constants -> stays in VGPRs (rule #20 safe).
#define LOAD_TILE(AV, BV, KT) do {                                            \
    const float4* _s4 = (const float4*)(aptr + (KT) * 64);                    \
    AV[0] = _s4[0]; AV[1] = _s4[1]; AV[2] = _s4[2]; AV[3] = _s4[3];           \
    const u16x8* _s8 = (const u16x8*)(bptr + (KT) * 64);                      \
    BV[0] = _s8[0]; BV[1] = _s8[1]; BV[2] = _s8[2]; BV[3] = _s8[3];           \
} while (0)

#define STORE_TILE(AV, BV) do {                                               \
    u16x8 _w0, _w1;                                                           \
    _w0[0]=f2bf(AV[0].x); _w0[1]=f2bf(AV[0].y); _w0[2]=f2bf(AV[0].z); _w0[3]=f2bf(AV[0].w); \
    _w0[4]=f2bf(AV[1].x); _w0[5]=f2bf(AV[1].y); _w0[6]=f2bf(AV[1].z); _w0[7]=f2bf(AV[1].w); \
    _w1[0]=f2bf(AV[2].x); _w1[1]=f2bf(AV[2].y); _w1[2]=f2bf(AV[2].z); _w1[3]=f2bf(AV[2].w); \
    _w1[4]=f2bf(AV[3].x); _w1[5]=f2bf(AV[3].y); _w1[6]=f2bf(AV[3].z); _w1[7]=f2bf(AV[3].w); \
    *(u16x8*)&smA[ar * LDT + aseg]     = _w0;                                 \
    *(u16x8*)&smA[ar * LDT + aseg + 8] = _w1;                                 \
    *(u16x8*)&smB[bn * LDT + bhalf]      = BV[0];                             \
    *(u16x8*)&smB[bn * LDT + bhalf + 8]  = BV[1];                             \
    *(u16x8*)&smB[bn * LDT + bhalf + 16] = BV[2];                             \
    *(u16x8*)&smB[bn * LDT + bhalf + 24] = BV[3];                             \
} while (0)

#define MFMA_TILE() do {                                                      \
    _Pragma("unroll")                                                         \
    for (int ks = 0; ks < 64; ks += 32) {                                     \
        bf16x8 af = *(const bf16x8*)&smA[(wid * 16 + l15) * LDT + ks + quad * 8]; \
        _Pragma("unroll")                                                     \
        for (int t = 0; t < 8; t++) {                                         \
            bf16x8 bfv = *(const bf16x8*)&smB[(t * 16 + l15) * LDT + ks + quad * 8]; \
            acc[t] = __builtin_amdgcn_mfma_f32_16x16x32_bf16(af, bfv, acc[t], 0, 0, 0); \
        }                                                                     \
    }                                                                         \
} while (0)

__global__ __launch_bounds__(256) void k_mega(
        const float* __restrict__ x,
        const int* __restrict__ erows, const int* __restrict__ ecols,
        const float* __restrict__ evals, const int* __restrict__ sn,
        const unsigned short* __restrict__ Wtw, const unsigned short* __restrict__ Wtb,
        int* __restrict__ cnt, int2* __restrict__ csr_pad,
        unsigned short* __restrict__ ybuf, unsigned short* __restrict__ selfp) {
    __shared__ __align__(16) unsigned short smA[64 * LDT];
    __shared__ __align__(16) unsigned short smB[128 * LDT];
    const int tid = threadIdx.x;

    if (blockIdx.x < GSCAT) {
        int i = blockIdx.x * 256 + tid;          // 3125*256 == 800000 exactly
        int r = erows[i];
        int rank = atomicAdd(&cnt[r], 1);
        if (rank < CAP) {
            int2 cv;
            cv.x = ecols[i];
            cv.y = __builtin_bit_cast(int, evals[i]);
            csr_pad[r * CAP + rank] = cv;
        }
        return;
    }

    const int gb = blockIdx.x - GSCAT;
    const bool isBig = gb < GBIG;
    const int* rowidx = isBig ? nullptr : sn;
    const unsigned short* Bt = isBig ? Wtw : Wtb;
    unsigned short* Y = isBig ? ybuf : selfp;
    const int M = isBig ? N_SRC : N_DST;
    const int bid = isBig ? gb : gb - GBIG;

    const int lane = tid & 63, wid = tid >> 6;
    const int l15 = lane & 15, quad = lane >> 4;
    const int row0 = bid * 64;

    const int ar = tid >> 2, aseg = (tid & 3) * 16;
    int srow = row0 + ar;
    if (srow >= M) srow = M - 1;
    if (rowidx) srow = rowidx[srow];
    const float* aptr = x + (long)srow * 256 + aseg;
    const int bn = tid >> 1, bhalf = (tid & 1) * 32;
    const unsigned short* bptr = Bt + (long)bn * 256 + bhalf;

    f32x4 acc[8];
    #pragma unroll
    for (int t = 0; t < 8; t++) acc[t] = (f32x4){0.f, 0.f, 0.f, 0.f};

    // -------- depth-2 register-prefetched K pipeline (4 k-tiles of 64) --------
    float4 pa[4], qa[4];
    u16x8  pb[4], qb[4];

    LOAD_TILE(pa, pb, 0);          // tiles 0 and 1 in flight before any use
    LOAD_TILE(qa, qb, 1);

    // kt = 0
    STORE_TILE(pa, pb);            // waits only on tile-0 loads; tile 1 stays in flight
    __syncthreads();
    LOAD_TILE(pa, pb, 2);          // issue tile 2 under MFMA(0)+convert(1)
    MFMA_TILE();
    __syncthreads();
    // kt = 1
    STORE_TILE(qa, qb);
    __syncthreads();
    LOAD_TILE(qa, qb, 3);          // issue tile 3 under MFMA(1)+convert(2)
    MFMA_TILE();
    __syncthreads();
    // kt = 2
    STORE_TILE(pa, pb);
    __syncthreads();
    MFMA_TILE();
    __syncthreads();
    // kt = 3
    STORE_TILE(qa, qb);
    __syncthreads();
    MFMA_TILE();
    __syncthreads();

    #pragma unroll
    for (int t = 0; t < 8; t++)
        #pragma unroll
        for (int rg = 0; rg < 4; rg++)
            smB[(wid * 16 + quad * 4 + rg) * EPS + t * 16 + l15] = f2bf(acc[t][rg]);
    __syncthreads();
    const int orow = tid >> 2, oc0 = (tid & 3) * 32;
    if (row0 + orow < M) {
        unsigned short* dst = Y + (long)(row0 + orow) * 128 + oc0;
        #pragma unroll
        for (int i = 0; i < 4; i++)
            *(u16x8*)(dst + i * 8) = *(const u16x8*)&smB[orow * EPS + oc0 + i * 8];
    }
}

// ---------------- fused SpMM + bias + ELU + layernorm + affine ----------------
// 4 waves/block, one dst row per wave; row's <=64 edges load in ONE int2/lane.
// edge loop software-pipelined depth-2 (keep one gather in flight past the consume).
__global__ __launch_bounds__(256) void k_sage(const unsigned short* __restrict__ y,
                                              const unsigned short* __restrict__ selfp,
                                              const int* __restrict__ cnt,
                                              const int2* __restrict__ csr_pad,
                                              const float* __restrict__ bw,
                                              const float* __restrict__ bb,
                                              const float* __restrict__ scale,
                                              const float* __restrict__ offs,
                                              float* __restrict__ out) {
    const int tid = threadIdx.x, lane = tid & 63, wid = tid >> 6;
    const int row = blockIdx.x * 4 + wid;
    const int m = min(cnt[row], CAP);

    // coalesced edge batch: one int2 per lane
    int2 cv = (lane < m) ? csr_pad[(long)row * CAP + lane] : make_int2(0, 0);

    // self half (cols 0..127)
    unsigned spk = *(const unsigned*)(selfp + (long)row * 128 + lane * 2);
    float s0 = bf2f((unsigned short)(spk & 0xffff)) + bb[lane * 2];
    float s1 = bf2f((unsigned short)(spk >> 16))    + bb[lane * 2 + 1];
    s0 = s0 > 0.f ? s0 : expm1f(s0);
    s1 = s1 > 0.f ? s1 : expm1f(s1);

    // neigh half (cols 128..255): broadcast each edge, gather y row coalesced
    float a0 = 0.f, a1 = 0.f;
    if (m > 0) {
        int   c  = __shfl(cv.x, 0, 64);
        float v  = __builtin_bit_cast(float, __shfl(cv.y, 0, 64));
        unsigned pk = *(const unsigned*)(y + (long)c * 128 + lane * 2);
        for (int e = 1; e < m; e++) {
            int   cN = __shfl(cv.x, e, 64);
            float vN = __builtin_bit_cast(float, __shfl(cv.y, e, 64));
            unsigned pkN = *(const unsigned*)(y + (long)cN * 128 + lane * 2);
            a0 = fmaf(v, __builtin_bit_cast(float, pk << 16), a0);
            a1 = fmaf(v, __builtin_bit_cast(float, pk & 0xffff0000u), a1);
            v = vN; pk = pkN;
        }
        a0 = fmaf(v, __builtin_bit_cast(float, pk << 16), a0);
        a1 = fmaf(v, __builtin_bit_cast(float, pk & 0xffff0000u), a1);
    }
    a0 += bw[lane * 2];
    a1 += bw[lane * 2 + 1];
    a0 = a0 > 0.f ? a0 : expm1f(a0);
    a1 = a1 > 0.f ? a1 : expm1f(a1);

    // layernorm over 256 values (4 per lane)
    float s  = s0 + s1 + a0 + a1;
    float s2 = s0 * s0 + s1 * s1 + a0 * a0 + a1 * a1;
    #pragma unroll
    for (int o = 32; o > 0; o >>= 1) {
        s  += __shfl_xor(s,  o, 64);
        s2 += __shfl_xor(s2, o, 64);
    }
    float mean = s * (1.f / 256.f);
    float var  = s2 * (1.f / 256.f) - mean * mean;
    float rstd = rsqrtf(var + 1e-9f);

    float* orow = out + (long)row * 256;
    float2 w0, w1;
    w0.x = (s0 - mean) * rstd * scale[lane * 2]           + offs[lane * 2];
    w0.y = (s1 - mean) * rstd * scale[lane * 2 + 1]       + offs[lane * 2 + 1];
    w1.x = (a0 - mean) * rstd * scale[128 + lane * 2]     + offs[128 + lane * 2];
    w1.y = (a1 - mean) * rstd * scale[128 + lane * 2 + 1] + offs[128 + lane * 2 + 1];
    *(float2*)(orow + lane * 2)       = w0;
    *(float2*)(orow + 128 + lane * 2) = w1;
}

extern "C" void kernel_launch(void* const* d_in, const int* in_sizes, int n_in,
                              void* d_out, int out_size, void* d_ws, size_t ws_size,
                              hipStream_t stream) {
    const float* x     = (const float*)d_in[0];
    const int*   erows = (const int*)  d_in[1];
    const int*   ecols = (const int*)  d_in[2];
    const float* evals = (const float*)d_in[3];
    const int*   sn    = (const int*)  d_in[4];
    const float* Ww    = (const float*)d_in[5];
    const float* bw    = (const float*)d_in[6];
    const float* Wb    = (const float*)d_in[7];
    const float* bb    = (const float*)d_in[8];
    const float* scale = (const float*)d_in[9];
    const float* offs  = (const float*)d_in[10];
    float* out = (float*)d_out;

    char* ws = (char*)d_ws;
    int*   cnt     = (int*)  (ws + WS_CNT);
    unsigned short* Wtw   = (unsigned short*)(ws + WS_WTW);
    unsigned short* Wtb   = (unsigned short*)(ws + WS_WTB);
    unsigned short* selfp = (unsigned short*)(ws + WS_SELF);
    unsigned short* ybuf  = (unsigned short*)(ws + WS_Y);
    int2*  csr_pad = (int2*) (ws + WS_CSR);

    k_init <<<256, 256, 0, stream>>>(Ww, Wb, Wtw, Wtb, cnt);
    k_mega <<<GSCAT + GBIG + GSELF, 256, 0, stream>>>(x, erows, ecols, evals, sn,
                                                      Wtw, Wtb, cnt, csr_pad, ybuf, selfp);
    k_sage <<<N_DST / 4, 256, 0, stream>>>(ybuf, selfp, cnt, csr_pad,
                                           bw, bb, scale, offs, out);
}

// Round 3
// 421.081 us; speedup vs baseline: 1.0647x; 1.0470x over previous
//
#include <hip/hip_runtime.h>
#include <math.h>

#define N_SRC   200000
#define N_DST   50000
#define N_EDGES 800000
#define N_IN    256
#define N_OUT   128
#define CAP     64        // padded-CSR slots/row; P(deg>64 | Binom(800K,1/50K)) ~ 1e-18/row

// ---- workspace layout (bytes), all 16B-aligned ----
#define WS_CNT   0            // int[50000] (+pad)
#define WS_WTW   204800       // ushort[128*256] bf16 (W_w^T)
#define WS_WTB   270336       // ushort[128*256] bf16 (W_b^T)
#define WS_SELF  335872       // ushort[50000*128] bf16
#define WS_Y     13135872     // ushort[200000*128] bf16
#define WS_CSR   64335872     // int2[50000*64]
// total ~90 MB

typedef short  bf16x8 __attribute__((ext_vector_type(8)));
typedef unsigned short u16x8 __attribute__((ext_vector_type(8)));
typedef float  f32x4  __attribute__((ext_vector_type(4)));

__device__ inline unsigned short f2bf(float f) {
    unsigned u = __builtin_bit_cast(unsigned, f);
    u += 0x7fffu + ((u >> 16) & 1u);           // RNE
    return (unsigned short)(u >> 16);
}
__device__ inline float bf2f(unsigned short h) {
    return __builtin_bit_cast(float, (unsigned)h << 16);
}

// ---------------- init: weight transpose+bf16, zero cnt ----------------
// 256 blocks x 256 threads = 65536 = 2*128*256
__global__ __launch_bounds__(256) void k_init(const float* __restrict__ Ww,
                                              const float* __restrict__ Wb,
                                              unsigned short* __restrict__ Wtw,
                                              unsigned short* __restrict__ Wtb,
                                              int* __restrict__ cnt) {
    int tot = blockIdx.x * 256 + threadIdx.x;
    int sel = tot >> 15;
    int idx = tot & 32767;
    int n = idx >> 8, k = idx & 255;
    const float* src = sel ? Wb : Ww;
    unsigned short* dst = sel ? Wtb : Wtw;
    dst[n * 256 + k] = f2bf(src[k * 128 + n]);
    if (tot < N_DST) cnt[tot] = 0;
}

// ---------------- mega: scatter (padded CSR) + both MFMA GEMMs ----------------
// blocks [0,3125): scatter 800000 edges
// blocks [3125,6250): y = x @ W_w           (200000 rows)
// blocks [6250,7032): self = x[sn] @ W_b    (50000 rows)
//
// Occupancy-first GEMM: BK=32 subtiles, LDS = 16896 B (union of A|B staging and
// epilogue buffer) -> 8 blocks/CU (vs 3.3 at the old 33 KB). Latency hiding via
// TLP across independent blocks, NOT intra-block pipelining (compiler defeats it).
#define GSCAT 3125
#define GBIG  3125
#define GSELF 782
#define LDA 40          // LDS row stride in ushorts (80 B -> ~2-way bank alias)
#define EPS 132         // epilogue LDS stride

__global__ __launch_bounds__(256, 8) void k_mega(
        const float* __restrict__ x,
        const int* __restrict__ erows, const int* __restrict__ ecols,
        const float* __restrict__ evals, const int* __restrict__ sn,
        const unsigned short* __restrict__ Wtw, const unsigned short* __restrict__ Wtb,
        int* __restrict__ cnt, int2* __restrict__ csr_pad,
        unsigned short* __restrict__ ybuf, unsigned short* __restrict__ selfp) {
    // union buffer: staging (A: 64x40 = 2560 ush | B: 128x40 = 5120 ush = 7680)
    //               epilogue (64 x 132 = 8448 ush)  -> 8448 ush = 16896 B
    __shared__ __align__(16) unsigned short sm[8448];
    unsigned short* smA = sm;           // 64 rows x LDA
    unsigned short* smB = sm + 2560;    // 128 rows x LDA
    const int tid = threadIdx.x;

    if (blockIdx.x < GSCAT) {
        int i = blockIdx.x * 256 + tid;          // 3125*256 == 800000 exactly
        int r = erows[i];
        int rank = atomicAdd(&cnt[r], 1);
        if (rank < CAP) {
            int2 cv;
            cv.x = ecols[i];
            cv.y = __builtin_bit_cast(int, evals[i]);
            csr_pad[r * CAP + rank] = cv;
        }
        return;
    }

    const int gb = blockIdx.x - GSCAT;
    const bool isBig = gb < GBIG;
    const int* rowidx = isBig ? nullptr : sn;
    const unsigned short* Bt = isBig ? Wtw : Wtb;
    unsigned short* Y = isBig ? ybuf : selfp;
    const int M = isBig ? N_SRC : N_DST;
    const int bid = isBig ? gb : gb - GBIG;

    const int lane = tid & 63, wid = tid >> 6;
    const int l15 = lane & 15, quad = lane >> 4;
    const int row0 = bid * 64;

    // A staging map: 4 threads/row, 8 floats (32 B) each -> one u16x8 LDS write
    const int ar = tid >> 2, aseg = (tid & 3) * 8;
    int srow = row0 + ar;
    if (srow >= M) srow = M - 1;
    if (rowidx) srow = rowidx[srow];
    const float* aptr = x + (long)srow * 256 + aseg;
    // B staging map: 2 threads/row, 16 bf16 (32 B) each -> two u16x8 LDS writes
    const int bn = tid >> 1, bh = (tid & 1) * 16;
    const unsigned short* bptr = Bt + (long)bn * 256 + bh;

    unsigned short* smAw = &smA[ar * LDA + aseg];
    unsigned short* smBw = &smB[bn * LDA + bh];
    const unsigned short* smAr = &smA[(wid * 16 + l15) * LDA + quad * 8];

    f32x4 acc[8];
    #pragma unroll
    for (int t = 0; t < 8; t++) acc[t] = (f32x4){0.f, 0.f, 0.f, 0.f};

    for (int kt = 0; kt < 8; kt++) {
        const int k0 = kt * 32;
        {
            const float4* s4 = (const float4*)(aptr + k0);
            float4 v0 = s4[0], v1 = s4[1];
            u16x8 w;
            w[0]=f2bf(v0.x); w[1]=f2bf(v0.y); w[2]=f2bf(v0.z); w[3]=f2bf(v0.w);
            w[4]=f2bf(v1.x); w[5]=f2bf(v1.y); w[6]=f2bf(v1.z); w[7]=f2bf(v1.w);
            *(u16x8*)smAw = w;
        }
        {
            const u16x8* s8 = (const u16x8*)(bptr + k0);
            u16x8 b0 = s8[0], b1 = s8[1];
            *(u16x8*)smBw       = b0;
            *(u16x8*)(smBw + 8) = b1;
        }
        __syncthreads();
        bf16x8 af = *(const bf16x8*)smAr;
        #pragma unroll
        for (int t = 0; t < 8; t++) {
            bf16x8 bfv = *(const bf16x8*)&smB[(t * 16 + l15) * LDA + quad * 8];
            acc[t] = __builtin_amdgcn_mfma_f32_16x16x32_bf16(af, bfv, acc[t], 0, 0, 0);
        }
        __syncthreads();
    }

    #pragma unroll
    for (int t = 0; t < 8; t++)
        #pragma unroll
        for (int rg = 0; rg < 4; rg++)
            sm[(wid * 16 + quad * 4 + rg) * EPS + t * 16 + l15] = f2bf(acc[t][rg]);
    __syncthreads();
    const int orow = tid >> 2, oc0 = (tid & 3) * 32;
    if (row0 + orow < M) {
        unsigned short* dst = Y + (long)(row0 + orow) * 128 + oc0;
        #pragma unroll
        for (int i = 0; i < 4; i++)
            *(u16x8*)(dst + i * 8) = *(const u16x8*)&sm[orow * EPS + oc0 + i * 8];
    }
}

// ---------------- fused SpMM + bias + ELU + layernorm + affine ----------------
// 4 waves/block, one dst row per wave; row's <=64 edges load in ONE int2/lane.
// Gather loop runs 8-deep: 8 independent 256 B row-gathers in flight per group.
// Zero-padded CSR slots (c=0, v=0) make over-issue safe: fmaf adds 0.
#define GATHER(j) \
    int   c##j = __shfl(cv.x, e0 + j, 64); \
    float v##j = __builtin_bit_cast(float, __shfl(cv.y, e0 + j, 64)); \
    unsigned p##j = *(const unsigned*)(y + (long)c##j * 128 + (lane << 1));
#define ACCUM(j) \
    a0 = fmaf(v##j, __builtin_bit_cast(float, p##j << 16), a0); \
    a1 = fmaf(v##j, __builtin_bit_cast(float, p##j & 0xffff0000u), a1);

__global__ __launch_bounds__(256) void k_sage(const unsigned short* __restrict__ y,
                                              const unsigned short* __restrict__ selfp,
                                              const int* __restrict__ cnt,
                                              const int2* __restrict__ csr_pad,
                                              const float* __restrict__ bw,
                                              const float* __restrict__ bb,
                                              const float* __restrict__ scale,
                                              const float* __restrict__ offs,
                                              float* __restrict__ out) {
    const int tid = threadIdx.x, lane = tid & 63, wid = tid >> 6;
    const int row = blockIdx.x * 4 + wid;
    const int m = min(cnt[row], CAP);

    // coalesced edge batch: one int2 per lane (zero-filled beyond m)
    int2 cv = (lane < m) ? csr_pad[(long)row * CAP + lane] : make_int2(0, 0);

    // self half (cols 0..127)
    unsigned spk = *(const unsigned*)(selfp + (long)row * 128 + lane * 2);
    float s0 = bf2f((unsigned short)(spk & 0xffff)) + bb[lane * 2];
    float s1 = bf2f((unsigned short)(spk >> 16))    + bb[lane * 2 + 1];
    s0 = s0 > 0.f ? s0 : expm1f(s0);
    s1 = s1 > 0.f ? s1 : expm1f(s1);

    // neigh half (cols 128..255): 8-deep pipelined gather
    float a0 = 0.f, a1 = 0.f;
    const int mm = (m + 7) & ~7;
    for (int e0 = 0; e0 < mm; e0 += 8) {
        GATHER(0) GATHER(1) GATHER(2) GATHER(3)
        GATHER(4) GATHER(5) GATHER(6) GATHER(7)
        ACCUM(0) ACCUM(1) ACCUM(2) ACCUM(3)
        ACCUM(4) ACCUM(5) ACCUM(6) ACCUM(7)
    }
    a0 += bw[lane * 2];
    a1 += bw[lane * 2 + 1];
    a0 = a0 > 0.f ? a0 : expm1f(a0);
    a1 = a1 > 0.f ? a1 : expm1f(a1);

    // layernorm over 256 values (4 per lane)
    float s  = s0 + s1 + a0 + a1;
    float s2 = s0 * s0 + s1 * s1 + a0 * a0 + a1 * a1;
    #pragma unroll
    for (int o = 32; o > 0; o >>= 1) {
        s  += __shfl_xor(s,  o, 64);
        s2 += __shfl_xor(s2, o, 64);
    }
    float mean = s * (1.f / 256.f);
    float var  = s2 * (1.f / 256.f) - mean * mean;
    float rstd = rsqrtf(var + 1e-9f);

    float* orow = out + (long)row * 256;
    float2 w0, w1;
    w0.x = (s0 - mean) * rstd * scale[lane * 2]           + offs[lane * 2];
    w0.y = (s1 - mean) * rstd * scale[lane * 2 + 1]       + offs[lane * 2 + 1];
    w1.x = (a0 - mean) * rstd * scale[128 + lane * 2]     + offs[128 + lane * 2];
    w1.y = (a1 - mean) * rstd * scale[128 + lane * 2 + 1] + offs[128 + lane * 2 + 1];
    *(float2*)(orow + lane * 2)       = w0;
    *(float2*)(orow + 128 + lane * 2) = w1;
}

extern "C" void kernel_launch(void* const* d_in, const int* in_sizes, int n_in,
                              void* d_out, int out_size, void* d_ws, size_t ws_size,
                              hipStream_t stream) {
    const float* x     = (const float*)d_in[0];
    const int*   erows = (const int*)  d_in[1];
    const int*   ecols = (const int*)  d_in[2];
    const float* evals = (const float*)d_in[3];
    const int*   sn    = (const int*)  d_in[4];
    const float* Ww    = (const float*)d_in[5];
    const float* bw    = (const float*)d_in[6];
    const float* Wb    = (const float*)d_in[7];
    const float* bb    = (const float*)d_in[8];
    const float* scale = (const float*)d_in[9];
    const float* offs  = (const float*)d_in[10];
    float* out = (float*)d_out;

    char* ws = (char*)d_ws;
    int*   cnt     = (int*)  (ws + WS_CNT);
    unsigned short* Wtw   = (unsigned short*)(ws + WS_WTW);
    unsigned short* Wtb   = (unsigned short*)(ws + WS_WTB);
    unsigned short* selfp = (unsigned short*)(ws + WS_SELF);
    unsigned short* ybuf  = (unsigned short*)(ws + WS_Y);
    int2*  csr_pad = (int2*) (ws + WS_CSR);

    k_init <<<256, 256, 0, stream>>>(Ww, Wb, Wtw, Wtb, cnt);
    k_mega <<<GSCAT + GBIG + GSELF, 256, 0, stream>>>(x, erows, ecols, evals, sn,
                                                      Wtw, Wtb, cnt, csr_pad, ybuf, selfp);
    k_sage <<<N_DST / 4, 256, 0, stream>>>(ybuf, selfp, cnt, csr_pad,
                                           bw, bb, scale, offs, out);
}